// Round 10
// baseline (336.948 us; speedup 1.0000x reference)
//
#include <hip/hip_runtime.h>
#include <hip/hip_bf16.h>

#define NT 65536   // text rows (M)
#define NL 1024    // label rows (N)
#define DD 256     // feature dim (K)

#define BM 128
#define BN 128
#define BK 64
#define TPB 16     // M-tiles per block (persistent strip)

typedef __attribute__((ext_vector_type(4))) float f32x4;
typedef __attribute__((ext_vector_type(8))) short bf16x8;

__device__ inline short f2bf(float x) {
    union { __hip_bfloat16 b; short s; } u;
    u.b = __float2bfloat16(x);   // RNE
    return u.s;
}

__device__ inline void gload_lds16(const void* g, void* l) {
    __builtin_amdgcn_global_load_lds((const __attribute__((address_space(1))) void*)g,
                                     (__attribute__((address_space(3))) void*)l,
                                     16, 0, 0);
}

// ---------------- prep: bf16 conversion + reciprocal norms ----------------
// fp32 source read non-temporally (never reused -> don't pollute L2).
__global__ __launch_bounds__(256) void prep_k(const float* __restrict__ A,
                                              const float* __restrict__ Bm,
                                              short* __restrict__ Abf,
                                              short* __restrict__ Bbf,
                                              float* __restrict__ rt,
                                              float* __restrict__ rl) {
    int gw   = (blockIdx.x * 256 + threadIdx.x) >> 6;
    int lane = threadIdx.x & 63;
    if (gw >= NT + NL) return;
    const float* src = (gw < NT) ? (A + (size_t)gw * DD) : (Bm + (size_t)(gw - NT) * DD);
    short*       dst = (gw < NT) ? (Abf + (size_t)gw * DD) : (Bbf + (size_t)(gw - NT) * DD);
    f32x4 v = __builtin_nontemporal_load(reinterpret_cast<const f32x4*>(src) + lane);
    short4 o;
    o.x = f2bf(v[0]); o.y = f2bf(v[1]); o.z = f2bf(v[2]); o.w = f2bf(v[3]);
    reinterpret_cast<short4*>(dst)[lane] = o;
    float s = v[0]*v[0] + v[1]*v[1] + v[2]*v[2] + v[3]*v[3];
#pragma unroll
    for (int off = 32; off > 0; off >>= 1) s += __shfl_xor(s, off);
    if (lane == 0) {
        float r = 1.0f / fmaxf(sqrtf(s), 1e-20f);
        if (gw < NT) rt[gw] = r; else rl[gw - NT] = r;
    }
}

// ---------------- persistent-strip bf16 GEMM, 4-ahead ring-5 pipeline -----
// R9 structure, but A ring deepened to 5 buffers with 4-ahead prefetch and
// stage issue AFTER the barrier: all four of tile t+1's stages precede tile
// t's epilogue stores in the VMEM queue, so every steady wait (vmcnt(38))
// targets a stage OLDER than the stores -> stores drain at natural HBM pace
// across ~5 phases instead of being force-drained in 3 (R8/R9's ~19us idle).
__global__ __launch_bounds__(512, 2) void cosim_bf_k(const short* __restrict__ Abf,
                                                     const short* __restrict__ Bbf,
                                                     const float* __restrict__ rt,
                                                     const float* __restrict__ rl,
                                                     float* __restrict__ C) {
    __shared__ short Bs[BN * DD];        // 64 KB, full-K B tile
    __shared__ short As[5][BM * BK];     // 80 KB, 5-deep A ring
    __shared__ float rnA[TPB * BM];      // 8 KB
    __shared__ float rnB[BN];            // 0.5 KB   (total 152.5 KB < 160)

    const int tid  = threadIdx.x;
    const int lane = tid & 63;
    const int w    = tid >> 6;       // 0..7
    const int wr   = w >> 2;         // wave row 0..1 (64 rows)
    const int wc   = w & 3;          // wave col 0..3 (32 cols)

    const int xcd   = blockIdx.x & 7;
    const int g2    = blockIdx.x >> 3;   // 0..31
    const int bx    = g2 & 7;
    const int sub   = g2 >> 3;           // 0..3
    const int strip = xcd * 4 + sub;     // 0..31
    const int m0b   = strip * (TPB * BM);
    const int l0    = bx * BN;

    // ---- stage B (full K), source-chunk XOR swizzle ----
    {
        const int r2 = lane >> 5;
        const int ch = lane & 31;
#pragma unroll
        for (int i = 0; i < 8; ++i) {
            int rbase = w * 16 + i * 2;
            int row   = rbase + r2;
            int cg    = ch ^ (row & 7);
            gload_lds16(Bbf + (size_t)(l0 + row) * DD + cg * 8, &Bs[rbase * DD]);
        }
    }
    // ---- preload reciprocal norms into LDS ----
#pragma unroll
    for (int i = 0; i < 4; ++i) {
        int r = tid + i * 512;
        rnA[r] = rt[m0b + r];
    }
    if (tid < BN) rnB[tid] = rl[l0 + tid];
    __syncthreads();                     // drains all init vmem/lds -> queue clean

    // ---- A staging: stage g = tile (g>>2), k-slice (g&3) -> buffer buf ----
    const int r8  = lane >> 3;
    const int ch8 = lane & 7;
    const int cg8 = ch8 ^ r8;
    auto stageA = [&](int g, int buf) {
        const short* base = Abf + (size_t)(m0b + (g >> 2) * BM) * DD + (g & 3) * BK;
        short* dst = As[buf];
#pragma unroll
        for (int i = 0; i < 2; ++i) {
            int rbase = w * 16 + i * 8;
            gload_lds16(base + (size_t)(rbase + r8) * DD + cg8 * 8, &dst[rbase * BK]);
        }
    };

    // prologue: buffers for phases 0..3
    stageA(0, 0); stageA(1, 1); stageA(2, 2); stageA(3, 3);
    int bread  = 0;   // buffer read in current phase g      (= g % 5)
    int bstage = 4;   // buffer written by stage of phase g  (= (g+4) % 5)

    const int fr = lane & 15;
    const int fq = lane >> 4;
    const int cc = lane & 15;

#pragma unroll 1
    for (int t = 0; t < TPB; ++t) {
        f32x4 acc[4][2] = {};
#pragma unroll
        for (int kt = 0; kt < 4; ++kt) {
            const int g = t * 4 + kt;
            // wait for own sA(g) DMAs (oldest in queue; stores are younger)
            if (t == 0) {
                asm volatile("s_waitcnt vmcnt(6)" ::: "memory");
            } else if (t == TPB - 1) {
                if      (kt == 0) asm volatile("s_waitcnt vmcnt(38)" ::: "memory");
                else if (kt == 1) asm volatile("s_waitcnt vmcnt(36)" ::: "memory");
                else if (kt == 2) asm volatile("s_waitcnt vmcnt(34)" ::: "memory");
                else              asm volatile("s_waitcnt vmcnt(32)" ::: "memory");
            } else {
                asm volatile("s_waitcnt vmcnt(38)" ::: "memory");
            }
            __builtin_amdgcn_s_barrier();   // all waves' sA(g) landed

            // issue next stage AFTER barrier (laggards done reading (g-1)%5)
            if (t < TPB - 1) stageA(g + 4, bstage);
            bstage = (bstage == 4) ? 0 : bstage + 1;

            const short* A_ = As[bread];
            bread = (bread == 4) ? 0 : bread + 1;
#pragma unroll
            for (int ks = 0; ks < 2; ++ks) {
                bf16x8 af[4], bf2[2];
#pragma unroll
                for (int i = 0; i < 4; ++i) {
                    int row = wr * 64 + i * 16 + fr;
                    int ck  = (ks * 4 + fq) ^ (row & 7);        // deswizzle
                    af[i] = *reinterpret_cast<const bf16x8*>(&A_[row * BK + ck * 8]);
                }
#pragma unroll
                for (int j = 0; j < 2; ++j) {
                    int row = wc * 32 + j * 16 + fr;
                    int c   = kt * 8 + ks * 4 + fq;              // full-K chunk
                    int ck  = c ^ (row & 7);
                    bf2[j] = *reinterpret_cast<const bf16x8*>(&Bs[row * DD + ck * 8]);
                }
#pragma unroll
                for (int i = 0; i < 4; ++i)
#pragma unroll
                    for (int j = 0; j < 2; ++j)
                        acc[i][j] = __builtin_amdgcn_mfma_f32_16x16x32_bf16(
                            af[i], bf2[j], acc[i][j], 0, 0, 0);
            }
        }

        // epilogue tile t — non-temporal stores (no L2 allocate)
        const int m0 = m0b + t * BM;
#pragma unroll
        for (int i = 0; i < 4; ++i) {
#pragma unroll
            for (int rr = 0; rr < 4; ++rr) {
                int lr = wr * 64 + i * 16 + fq * 4 + rr;
                float rs = rnA[t * BM + lr];
                float* crow = C + (size_t)(m0 + lr) * NL + l0;
#pragma unroll
                for (int j = 0; j < 2; ++j) {
                    int lc = wc * 32 + j * 16 + cc;
                    __builtin_nontemporal_store(acc[i][j][rr] * rs * rnB[lc], &crow[lc]);
                }
            }
        }
    }
}

// ---------------- fallback (round-1 fused path, ws too small) -------------
__global__ __launch_bounds__(256) void norms_k(const float* __restrict__ A,
                                               const float* __restrict__ Bm,
                                               float* __restrict__ rt,
                                               float* __restrict__ rl) {
    int gw   = (blockIdx.x * 256 + threadIdx.x) >> 6;
    int lane = threadIdx.x & 63;
    if (gw >= NT + NL) return;
    const float* src = (gw < NT) ? (A + (size_t)gw * DD) : (Bm + (size_t)(gw - NT) * DD);
    float4 v = reinterpret_cast<const float4*>(src)[lane];
    float s = v.x * v.x + v.y * v.y + v.z * v.z + v.w * v.w;
#pragma unroll
    for (int off = 32; off > 0; off >>= 1) s += __shfl_xor(s, off);
    if (lane == 0) {
        float r = 1.0f / fmaxf(sqrtf(s), 1e-20f);
        if (gw < NT) rt[gw] = r; else rl[gw - NT] = r;
    }
}

__global__ __launch_bounds__(256, 2) void cosim_fused_k(const float* __restrict__ A,
                                                        const float* __restrict__ Bm,
                                                        const float* __restrict__ rt,
                                                        const float* __restrict__ rl,
                                                        float* __restrict__ C) {
    __shared__ short As[BM * BK];
    __shared__ short Bs[BN * BK];
    const int tid  = threadIdx.x;
    const int lane = tid & 63;
    const int wid  = tid >> 6;
    const int wr   = wid >> 1;
    const int wc   = wid & 1;
    const int orig = blockIdx.x;
    const int id   = (orig & 7) * (4096 / 8) + (orig >> 3);
    const int bx   = id & 7;
    const int by   = id >> 3;
    const int m0 = by * BM;
    const int l0 = bx * BN;
    const int srow = tid >> 4;
    const int sc4  = tid & 15;
    f32x4 ra[8], rb[8];
    auto loadg = [&](int kt) {
        const float* pa = A  + (size_t)m0 * DD + kt * BK;
        const float* pb = Bm + (size_t)l0 * DD + kt * BK;
#pragma unroll
        for (int i = 0; i < 8; ++i) {
            int row = srow + i * 16;
            ra[i] = reinterpret_cast<const f32x4*>(pa + (size_t)row * DD)[sc4];
            rb[i] = reinterpret_cast<const f32x4*>(pb + (size_t)row * DD)[sc4];
        }
    };
    auto stash = [&]() {
#pragma unroll
        for (int i = 0; i < 8; ++i) {
            int row = srow + i * 16;
            short4 pa, pb;
            pa.x = f2bf(ra[i][0]); pa.y = f2bf(ra[i][1]);
            pa.z = f2bf(ra[i][2]); pa.w = f2bf(ra[i][3]);
            pb.x = f2bf(rb[i][0]); pb.y = f2bf(rb[i][1]);
            pb.z = f2bf(rb[i][2]); pb.w = f2bf(rb[i][3]);
            *reinterpret_cast<short4*>(&As[row * BK + sc4 * 4]) = pa;
            *reinterpret_cast<short4*>(&Bs[row * BK + sc4 * 4]) = pb;
        }
    };
    f32x4 acc[4][4] = {};
    loadg(0);
#pragma unroll
    for (int kt = 0; kt < DD / BK; ++kt) {
        __syncthreads();
        stash();
        __syncthreads();
        if (kt < DD / BK - 1) loadg(kt + 1);
#pragma unroll
        for (int ks = 0; ks < 2; ++ks) {
            bf16x8 af[4], bfr[4];
            const int kof = ks * 32 + (lane >> 4) * 8;
            const int ar  = wr * 64 + (lane & 15);
            const int bc  = wc * 64 + (lane & 15);
#pragma unroll
            for (int i = 0; i < 4; ++i)
                af[i] = *reinterpret_cast<const bf16x8*>(&As[(ar + i * 16) * BK + kof]);
#pragma unroll
            for (int j = 0; j < 4; ++j)
                bfr[j] = *reinterpret_cast<const bf16x8*>(&Bs[(bc + j * 16) * BK + kof]);
#pragma unroll
            for (int i = 0; i < 4; ++i)
#pragma unroll
                for (int j = 0; j < 4; ++j)
                    acc[i][j] = __builtin_amdgcn_mfma_f32_16x16x32_bf16(
                        af[i], bfr[j], acc[i][j], 0, 0, 0);
        }
    }
    const int crow0 = m0 + wr * 64;
    const int ccol0 = l0 + wc * 64;
    const int rq = lane >> 4;
    const int cc = lane & 15;
#pragma unroll
    for (int i = 0; i < 4; ++i) {
#pragma unroll
        for (int r = 0; r < 4; ++r) {
            int row = crow0 + i * 16 + rq * 4 + r;
            float rsc = rt[row];
            float* crow = C + (size_t)row * NL;
#pragma unroll
            for (int j = 0; j < 4; ++j) {
                int col = ccol0 + j * 16 + cc;
                crow[col] = acc[i][j][r] * rsc * rl[col];
            }
        }
    }
}

extern "C" void kernel_launch(void* const* d_in, const int* in_sizes, int n_in,
                              void* d_out, int out_size, void* d_ws, size_t ws_size,
                              hipStream_t stream) {
    const float* A  = (const float*)d_in[0];   // [65536,256] fp32
    const float* Bm = (const float*)d_in[1];   // [1024,256]  fp32
    float* C = (float*)d_out;                  // [65536,1024] fp32

    const size_t abf_elems = (size_t)NT * DD;
    const size_t bbf_elems = (size_t)NL * DD;
    const size_t need = (abf_elems + bbf_elems) * sizeof(short)
                      + (NT + NL) * sizeof(float);

    if (ws_size >= need) {
        short* Abf = (short*)d_ws;
        short* Bbf = Abf + abf_elems;
        float* rt  = (float*)(Bbf + bbf_elems);
        float* rl  = rt + NT;
        prep_k<<<(NT + NL) / 4, 256, 0, stream>>>(A, Bm, Abf, Bbf, rt, rl);
        cosim_bf_k<<<256, 512, 0, stream>>>(Abf, Bbf, rt, rl, C);
    } else {
        float* rt = (float*)d_ws;
        float* rl = rt + NT;
        norms_k<<<(NT + NL) / 4, 256, 0, stream>>>(A, Bm, rt, rl);
        cosim_fused_k<<<(NL / BN) * (NT / BM), 256, 0, stream>>>(A, Bm, rt, rl, C);
    }
}

// Round 11
// 318.676 us; speedup vs baseline: 1.0573x; 1.0573x over previous
//
#include <hip/hip_runtime.h>
#include <hip/hip_bf16.h>

#define NT 65536   // text rows (M)
#define NL 1024    // label rows (N)
#define DD 256     // feature dim (K)

#define BM 128
#define BN 128
#define BK 64
#define TPB 16     // M-tiles per block (persistent strip)

typedef __attribute__((ext_vector_type(4))) float f32x4;
typedef __attribute__((ext_vector_type(8))) short bf16x8;

__device__ inline short f2bf(float x) {
    union { __hip_bfloat16 b; short s; } u;
    u.b = __float2bfloat16(x);   // RNE
    return u.s;
}

__device__ inline void gload_lds16(const void* g, void* l) {
    __builtin_amdgcn_global_load_lds((const __attribute__((address_space(1))) void*)g,
                                     (__attribute__((address_space(3))) void*)l,
                                     16, 0, 0);
}

// ---------------- prep: bf16 conversion + reciprocal norms ----------------
__global__ __launch_bounds__(256) void prep_k(const float* __restrict__ A,
                                              const float* __restrict__ Bm,
                                              short* __restrict__ Abf,
                                              short* __restrict__ Bbf,
                                              float* __restrict__ rt,
                                              float* __restrict__ rl) {
    int gw   = (blockIdx.x * 256 + threadIdx.x) >> 6;
    int lane = threadIdx.x & 63;
    if (gw >= NT + NL) return;
    const float* src = (gw < NT) ? (A + (size_t)gw * DD) : (Bm + (size_t)(gw - NT) * DD);
    short*       dst = (gw < NT) ? (Abf + (size_t)gw * DD) : (Bbf + (size_t)(gw - NT) * DD);
    float4 v = reinterpret_cast<const float4*>(src)[lane];
    short4 o;
    o.x = f2bf(v.x); o.y = f2bf(v.y); o.z = f2bf(v.z); o.w = f2bf(v.w);
    reinterpret_cast<short4*>(dst)[lane] = o;
    float s = v.x * v.x + v.y * v.y + v.z * v.z + v.w * v.w;
#pragma unroll
    for (int off = 32; off > 0; off >>= 1) s += __shfl_xor(s, off);
    if (lane == 0) {
        float r = 1.0f / fmaxf(sqrtf(s), 1e-20f);
        if (gw < NT) rt[gw] = r; else rl[gw - NT] = r;
    }
}

// ---------------- persistent-strip bf16 GEMM, paced-store pipeline --------
// R9 base (ring-4, stage-before-wait, nt stores) + accumulator ping-pong:
// tile t-1's 32 stores are issued 8-per-phase during tile t, after the
// barrier and before the next stage issue. Every wait then targets a stage
// whose younger-op window is exactly 20 (8 st + 2 stage + 8 st + 2 stage),
// so no wait ever forces a 32-store burst drain; stores retire at HBM pace
// spread across 4 phases. Queue max 22 << 63 (no issue throttle, R10's bug).
__global__ __launch_bounds__(512, 2) void cosim_bf_k(const short* __restrict__ Abf,
                                                     const short* __restrict__ Bbf,
                                                     const float* __restrict__ rt,
                                                     const float* __restrict__ rl,
                                                     float* __restrict__ C) {
    __shared__ short Bs[BN * DD];        // 64 KB, full-K B tile
    __shared__ short As[4][BM * BK];     // 64 KB, 4-deep A ring
    __shared__ float rnA[TPB * BM];      // 8 KB
    __shared__ float rnB[BN];            // 0.5 KB

    const int tid  = threadIdx.x;
    const int lane = tid & 63;
    const int w    = tid >> 6;       // 0..7
    const int wr   = w >> 2;         // wave row 0..1 (64 rows)
    const int wc   = w & 3;          // wave col 0..3 (32 cols)

    const int xcd   = blockIdx.x & 7;
    const int g2    = blockIdx.x >> 3;   // 0..31
    const int bx    = g2 & 7;
    const int sub   = g2 >> 3;           // 0..3
    const int strip = xcd * 4 + sub;     // 0..31
    const int m0b   = strip * (TPB * BM);
    const int l0    = bx * BN;

    // ---- stage B (full K), source-chunk XOR swizzle ----
    {
        const int r2 = lane >> 5;
        const int ch = lane & 31;
#pragma unroll
        for (int i = 0; i < 8; ++i) {
            int rbase = w * 16 + i * 2;
            int row   = rbase + r2;
            int cg    = ch ^ (row & 7);
            gload_lds16(Bbf + (size_t)(l0 + row) * DD + cg * 8, &Bs[rbase * DD]);
        }
    }
    // ---- preload reciprocal norms into LDS ----
#pragma unroll
    for (int i = 0; i < 4; ++i) {
        int r = tid + i * 512;
        rnA[r] = rt[m0b + r];
    }
    if (tid < BN) rnB[tid] = rl[l0 + tid];
    __syncthreads();                     // drains init vmem/lds -> queue clean

    // ---- A staging: stage g = tile (g>>2), k-slice (g&3) -> ring buf ----
    const int r8  = lane >> 3;
    const int ch8 = lane & 7;
    const int cg8 = ch8 ^ r8;
    auto stageA = [&](int g, int buf) {
        const short* base = Abf + (size_t)(m0b + (g >> 2) * BM) * DD + (g & 3) * BK;
        short* dst = As[buf];
#pragma unroll
        for (int i = 0; i < 2; ++i) {
            int rbase = w * 16 + i * 8;
            gload_lds16(base + (size_t)(rbase + r8) * DD + cg8 * 8, &dst[rbase * BK]);
        }
    };

    stageA(0, 0);
    stageA(1, 1);

    const int fr = lane & 15;
    const int fq = lane >> 4;
    const int cc = lane & 15;
    const f32x4 z4 = {0.f, 0.f, 0.f, 0.f};

    f32x4 accA[4][2], accB[4][2];

    // store one quarter (i-block) of tile tp from prev-acc, non-temporal
    auto store_q = [&](int tp, int i, f32x4 (&prev)[4][2]) {
        const int m0 = m0b + tp * BM;
#pragma unroll
        for (int rr = 0; rr < 4; ++rr) {
            int lr = wr * 64 + i * 16 + fq * 4 + rr;
            float rs = rnA[tp * BM + lr];
            float* crow = C + (size_t)(m0 + lr) * NL + l0;
#pragma unroll
            for (int j = 0; j < 2; ++j) {
                int lc = wc * 32 + j * 16 + cc;
                __builtin_nontemporal_store(prev[i][j][rr] * rs * rnB[lc], &crow[lc]);
            }
        }
    };

    auto tile = [&](int t, f32x4 (&acc)[4][2], f32x4 (&prev)[4][2], bool doStore) {
#pragma unroll
        for (int i = 0; i < 4; ++i)
#pragma unroll
            for (int j = 0; j < 2; ++j) acc[i][j] = z4;

#pragma unroll
        for (int kt = 0; kt < 4; ++kt) {
            const int g = t * 4 + kt;
            if (g + 2 < 4 * TPB) stageA(g + 2, (kt + 2) & 3);
            // counted waits: guarantee stage g retired; younger-op window
            // derived per-phase (see commit journal). Never force >8 stores.
            if (t == 0) {
                asm volatile("s_waitcnt vmcnt(4)" ::: "memory");
            } else if (t == 1) {
                if (kt == 0)      asm volatile("s_waitcnt vmcnt(4)" ::: "memory");
                else if (kt == 1) asm volatile("s_waitcnt vmcnt(12)" ::: "memory");
                else              asm volatile("s_waitcnt vmcnt(20)" ::: "memory");
            } else if (t == TPB - 1 && kt == 2) {
                asm volatile("s_waitcnt vmcnt(18)" ::: "memory");
            } else if (t == TPB - 1 && kt == 3) {
                asm volatile("s_waitcnt vmcnt(16)" ::: "memory");
            } else {
                asm volatile("s_waitcnt vmcnt(20)" ::: "memory");
            }
            __builtin_amdgcn_s_barrier();   // all waves' stage(g) landed

            if (doStore) store_q(t - 1, kt, prev);   // 8 paced stores

            const short* A_ = As[kt];
#pragma unroll
            for (int ks = 0; ks < 2; ++ks) {
                bf16x8 af[4], bf2[2];
#pragma unroll
                for (int i = 0; i < 4; ++i) {
                    int row = wr * 64 + i * 16 + fr;
                    int ck  = (ks * 4 + fq) ^ (row & 7);        // deswizzle
                    af[i] = *reinterpret_cast<const bf16x8*>(&A_[row * BK + ck * 8]);
                }
#pragma unroll
                for (int j = 0; j < 2; ++j) {
                    int row = wc * 32 + j * 16 + fr;
                    int c   = kt * 8 + ks * 4 + fq;              // full-K chunk
                    int ck  = c ^ (row & 7);
                    bf2[j] = *reinterpret_cast<const bf16x8*>(&Bs[row * DD + ck * 8]);
                }
#pragma unroll
                for (int i = 0; i < 4; ++i)
#pragma unroll
                    for (int j = 0; j < 2; ++j)
                        acc[i][j] = __builtin_amdgcn_mfma_f32_16x16x32_bf16(
                            af[i], bf2[j], acc[i][j], 0, 0, 0);
            }
        }
    };

#pragma unroll 1
    for (int tp = 0; tp < TPB; tp += 2) {
        tile(tp,     accA, accB, tp > 0);   // even tile -> accA, drains accB
        tile(tp + 1, accB, accA, true);     // odd  tile -> accB, drains accA
    }
    // final drain: tile 15 (odd -> accB)
#pragma unroll
    for (int i = 0; i < 4; ++i) store_q(TPB - 1, i, accB);
}

// ---------------- fallback (round-1 fused path, ws too small) -------------
__global__ __launch_bounds__(256) void norms_k(const float* __restrict__ A,
                                               const float* __restrict__ Bm,
                                               float* __restrict__ rt,
                                               float* __restrict__ rl) {
    int gw   = (blockIdx.x * 256 + threadIdx.x) >> 6;
    int lane = threadIdx.x & 63;
    if (gw >= NT + NL) return;
    const float* src = (gw < NT) ? (A + (size_t)gw * DD) : (Bm + (size_t)(gw - NT) * DD);
    float4 v = reinterpret_cast<const float4*>(src)[lane];
    float s = v.x * v.x + v.y * v.y + v.z * v.z + v.w * v.w;
#pragma unroll
    for (int off = 32; off > 0; off >>= 1) s += __shfl_xor(s, off);
    if (lane == 0) {
        float r = 1.0f / fmaxf(sqrtf(s), 1e-20f);
        if (gw < NT) rt[gw] = r; else rl[gw - NT] = r;
    }
}

__global__ __launch_bounds__(256, 2) void cosim_fused_k(const float* __restrict__ A,
                                                        const float* __restrict__ Bm,
                                                        const float* __restrict__ rt,
                                                        const float* __restrict__ rl,
                                                        float* __restrict__ C) {
    __shared__ short As[BM * BK];
    __shared__ short Bs[BN * BK];
    const int tid  = threadIdx.x;
    const int lane = tid & 63;
    const int wid  = tid >> 6;
    const int wr   = wid >> 1;
    const int wc   = wid & 1;
    const int orig = blockIdx.x;
    const int id   = (orig & 7) * (4096 / 8) + (orig >> 3);
    const int bx   = id & 7;
    const int by   = id >> 3;
    const int m0 = by * BM;
    const int l0 = bx * BN;
    const int srow = tid >> 4;
    const int sc4  = tid & 15;
    f32x4 ra[8], rb[8];
    auto loadg = [&](int kt) {
        const float* pa = A  + (size_t)m0 * DD + kt * BK;
        const float* pb = Bm + (size_t)l0 * DD + kt * BK;
#pragma unroll
        for (int i = 0; i < 8; ++i) {
            int row = srow + i * 16;
            ra[i] = reinterpret_cast<const f32x4*>(pa + (size_t)row * DD)[sc4];
            rb[i] = reinterpret_cast<const f32x4*>(pb + (size_t)row * DD)[sc4];
        }
    };
    auto stash = [&]() {
#pragma unroll
        for (int i = 0; i < 8; ++i) {
            int row = srow + i * 16;
            short4 pa, pb;
            pa.x = f2bf(ra[i][0]); pa.y = f2bf(ra[i][1]);
            pa.z = f2bf(ra[i][2]); pa.w = f2bf(ra[i][3]);
            pb.x = f2bf(rb[i][0]); pb.y = f2bf(rb[i][1]);
            pb.z = f2bf(rb[i][2]); pb.w = f2bf(rb[i][3]);
            *reinterpret_cast<short4*>(&As[row * BK + sc4 * 4]) = pa;
            *reinterpret_cast<short4*>(&Bs[row * BK + sc4 * 4]) = pb;
        }
    };
    f32x4 acc[4][4] = {};
    loadg(0);
#pragma unroll
    for (int kt = 0; kt < DD / BK; ++kt) {
        __syncthreads();
        stash();
        __syncthreads();
        if (kt < DD / BK - 1) loadg(kt + 1);
#pragma unroll
        for (int ks = 0; ks < 2; ++ks) {
            bf16x8 af[4], bfr[4];
            const int kof = ks * 32 + (lane >> 4) * 8;
            const int ar  = wr * 64 + (lane & 15);
            const int bc  = wc * 64 + (lane & 15);
#pragma unroll
            for (int i = 0; i < 4; ++i)
                af[i] = *reinterpret_cast<const bf16x8*>(&As[(ar + i * 16) * BK + kof]);
#pragma unroll
            for (int j = 0; j < 4; ++j)
                bfr[j] = *reinterpret_cast<const bf16x8*>(&Bs[(bc + j * 16) * BK + kof]);
#pragma unroll
            for (int i = 0; i < 4; ++i)
#pragma unroll
                for (int j = 0; j < 4; ++j)
                    acc[i][j] = __builtin_amdgcn_mfma_f32_16x16x32_bf16(
                        af[i], bfr[j], acc[i][j], 0, 0, 0);
        }
    }
    const int crow0 = m0 + wr * 64;
    const int ccol0 = l0 + wc * 64;
    const int rq = lane >> 4;
    const int cc = lane & 15;
#pragma unroll
    for (int i = 0; i < 4; ++i) {
#pragma unroll
        for (int r = 0; r < 4; ++r) {
            int row = crow0 + i * 16 + rq * 4 + r;
            float rsc = rt[row];
            float* crow = C + (size_t)row * NL;
#pragma unroll
            for (int j = 0; j < 4; ++j) {
                int col = ccol0 + j * 16 + cc;
                crow[col] = acc[i][j][r] * rsc * rl[col];
            }
        }
    }
}

extern "C" void kernel_launch(void* const* d_in, const int* in_sizes, int n_in,
                              void* d_out, int out_size, void* d_ws, size_t ws_size,
                              hipStream_t stream) {
    const float* A  = (const float*)d_in[0];   // [65536,256] fp32
    const float* Bm = (const float*)d_in[1];   // [1024,256]  fp32
    float* C = (float*)d_out;                  // [65536,1024] fp32

    const size_t abf_elems = (size_t)NT * DD;
    const size_t bbf_elems = (size_t)NL * DD;
    const size_t need = (abf_elems + bbf_elems) * sizeof(short)
                      + (NT + NL) * sizeof(float);

    if (ws_size >= need) {
        short* Abf = (short*)d_ws;
        short* Bbf = Abf + abf_elems;
        float* rt  = (float*)(Bbf + bbf_elems);
        float* rl  = rt + NT;
        prep_k<<<(NT + NL) / 4, 256, 0, stream>>>(A, Bm, Abf, Bbf, rt, rl);
        cosim_bf_k<<<256, 512, 0, stream>>>(Abf, Bbf, rt, rl, C);
    } else {
        float* rt = (float*)d_ws;
        float* rl = rt + NT;
        norms_k<<<(NT + NL) / 4, 256, 0, stream>>>(A, Bm, rt, rl);
        cosim_fused_k<<<(NL / BN) * (NT / BM), 256, 0, stream>>>(A, Bm, rt, rl, C);
    }
}